// Round 1
// baseline (1120.833 us; speedup 1.0000x reference)
//
#include <hip/hip_runtime.h>

// LIF benchmark: xs = einsum('tbf,gf->tbg', S, W)  (fp32 GEMM, A=S [T*B,512], B=W [512,512], NT)
// then sequential scan over T with per-neuron (v,i) state and heaviside threshold.
// Outputs: [z_final, z_final, v_final, i_final], each [128,512] fp32.
//
// R6 (this session R1): two changes on top of the proven R5 kernel:
//   1. GEMM A-operand register prefetch: issue next k-tile's A (S operand, HBM
//      ~900cy latency) right after the compute barrier so it lands during the
//      32-k compute (~16k cy). B (W, L2-hot ~200-300cy) stays at loop top.
//      Only +16 VGPR; prefetching B too would blow the 256-reg/wave budget at
//      2 waves/EU (acc[8][16]=128 in AGPR + 108 VGPR measured).
//   2. Launcher caps Tc at 256: xs chunk (67 MB) + S chunk (67 MB) + W (1 MB)
//      fit the 256 MB Infinity Cache, so the GEMM->scan xs handoff never does
//      the HBM round trip (scan was 1.4 TB/s effective on HBM re-read).
// Compute loop, store pattern, scan kernel: verbatim R5 (bit-exact, absmax 0.0).

#define T_DIM 1024
#define B_DIM 128
#define F_DIM 512
#define NB (B_DIM * F_DIM)  // 65536 neurons

// ---------------- GEMM: C[m][n] = sum_k A[m][k] * W[n][k] ----------------
// Block tile 128m x 256n, 256 threads, 8x16 micro-tile, KC=32, single-buffered
// LDS with A-side register prefetch pipeline.
#define TM 128
#define TN 256
#define KC 32
#define LDA_S 132  // As row pad
#define LDB_S 260  // Bs row pad

__global__ __launch_bounds__(256, 2)
void gemm_kernel(const float* __restrict__ A, const float* __restrict__ W,
                 float* __restrict__ C) {
    __shared__ float As[KC * LDA_S];  // [k][m]
    __shared__ float Bs[KC * LDB_S];  // [k][n]
    const int tid = threadIdx.x;
    const int m0 = blockIdx.x * TM;
    const int n0 = blockIdx.y * TN;
    const int tn4 = (tid & 15) * 4;  // b cols: tn4 + {0..3} + 64q, q=0..3
    const int tm4 = (tid >> 4) * 4;  // a rows: tm4 + {0..3} and +64
    const int srow = tid >> 3;       // staging row 0..31 (+32p)
    const int sk = (tid & 7) * 4;    // staging k 0,4,...,28

    float acc[8][16];
    #pragma unroll
    for (int i = 0; i < 8; ++i)
        #pragma unroll
        for (int j = 0; j < 16; ++j) acc[i][j] = 0.f;

    // prologue: A tile for k0=0 (consumed at the stores of iteration 0)
    float4 av[4];
    #pragma unroll
    for (int p = 0; p < 4; ++p)
        av[p] = *(const float4*)(A + (size_t)(m0 + srow + 32 * p) * F_DIM + sk);

    for (int k0 = 0; k0 < F_DIM; k0 += KC) {
        // B loads for this tile (W is L2/LLC-hot: short exposure at its stores)
        float4 bv[8];
        #pragma unroll
        for (int p = 0; p < 8; ++p)
            bv[p] = *(const float4*)(W + (size_t)(n0 + srow + 32 * p) * F_DIM + k0 + sk);
        __syncthreads();  // previous tile's compute done before overwrite
        // A stores first (av loaded a full tile ago -> vmcnt for it long since 0),
        // B stores last (gives bv maximal time in flight).
        #pragma unroll
        for (int p = 0; p < 4; ++p) {
            const int r = srow + 32 * p;
            As[(sk + 0) * LDA_S + r] = av[p].x;  As[(sk + 1) * LDA_S + r] = av[p].y;
            As[(sk + 2) * LDA_S + r] = av[p].z;  As[(sk + 3) * LDA_S + r] = av[p].w;
        }
        #pragma unroll
        for (int p = 0; p < 8; ++p) {
            const int r = srow + 32 * p;
            Bs[(sk + 0) * LDB_S + r] = bv[p].x;  Bs[(sk + 1) * LDB_S + r] = bv[p].y;
            Bs[(sk + 2) * LDB_S + r] = bv[p].z;  Bs[(sk + 3) * LDB_S + r] = bv[p].w;
        }
        __syncthreads();

        // prefetch NEXT tile's A: latency hides under the 32-k compute below
        if (k0 + KC < F_DIM) {
            #pragma unroll
            for (int p = 0; p < 4; ++p)
                av[p] = *(const float4*)(A + (size_t)(m0 + srow + 32 * p) * F_DIM
                                           + (k0 + KC) + sk);
        }

        #pragma unroll 4
        for (int k = 0; k < KC; ++k) {
            const float4 a0 = *(const float4*)(As + k * LDA_S + tm4);
            const float4 a1 = *(const float4*)(As + k * LDA_S + tm4 + 64);
            const float4 b0 = *(const float4*)(Bs + k * LDB_S + tn4);
            const float4 b1 = *(const float4*)(Bs + k * LDB_S + tn4 + 64);
            const float4 b2 = *(const float4*)(Bs + k * LDB_S + tn4 + 128);
            const float4 b3 = *(const float4*)(Bs + k * LDB_S + tn4 + 192);
            const float a[8] = {a0.x, a0.y, a0.z, a0.w, a1.x, a1.y, a1.z, a1.w};
            const float b[16] = {b0.x, b0.y, b0.z, b0.w, b1.x, b1.y, b1.z, b1.w,
                                 b2.x, b2.y, b2.z, b2.w, b3.x, b3.y, b3.z, b3.w};
            #pragma unroll
            for (int i = 0; i < 8; ++i)
                #pragma unroll
                for (int j = 0; j < 16; ++j)
                    acc[i][j] += a[i] * b[j];
        }
    }

    #pragma unroll
    for (int i = 0; i < 8; ++i) {
        const int m = m0 + ((i < 4) ? (tm4 + i) : (tm4 + 60 + i));  // tm4+64+(i-4)
        #pragma unroll
        for (int q = 0; q < 4; ++q) {
            const float4 c = make_float4(acc[i][4 * q + 0], acc[i][4 * q + 1],
                                         acc[i][4 * q + 2], acc[i][4 * q + 3]);
            *(float4*)(C + (size_t)m * F_DIM + n0 + tn4 + 64 * q) = c;
        }
    }
}

// ---------------- sequential LIF scan over a chunk of Tc steps ----------------
// Verbatim R3/R5 (passed): depth-32 register ring buffer.
// Explicit _rn intrinsics: forbid fma contraction (matches reference rounding).
#define DEPTH 32

__global__ __launch_bounds__(256)
void scan_kernel(const float* __restrict__ xs, float* __restrict__ vi,
                 float* __restrict__ out, int Tc, int first, int last) {
    const int j = blockIdx.x * 256 + threadIdx.x;  // neuron id, 0..NB-1
    float v, cur;
    if (first) { v = 0.f; cur = 0.f; }
    else       { v = vi[j]; cur = vi[NB + j]; }
    float z = 0.f;
    const float* pj = xs + j;

    if (Tc >= DEPTH && (Tc % DEPTH) == 0) {
        float buf[DEPTH];
        #pragma unroll
        for (int d = 0; d < DEPTH; ++d) buf[d] = pj[(size_t)d * NB];
        for (int tt = 0; tt < Tc; tt += DEPTH) {
            #pragma unroll
            for (int d = 0; d < DEPTH; ++d) {
                const float x = buf[d];
                int tn = tt + DEPTH + d;
                tn = (tn < Tc) ? tn : 0;          // clamped dead prefetch at tail
                buf[d] = pj[(size_t)tn * NB];
                const float vd = __fadd_rn(v, __fmul_rn(0.1f, __fsub_rn(cur, v)));
                const float id = __fadd_rn(cur, __fmul_rn(-0.2f, cur));
                const bool sp = vd > 1.0f;
                z = sp ? 1.f : 0.f;
                v = sp ? 0.f : vd;
                cur = __fadd_rn(id, x);
            }
        }
    } else {
        for (int t = 0; t < Tc; ++t) {
            const float x = pj[(size_t)t * NB];
            const float vd = __fadd_rn(v, __fmul_rn(0.1f, __fsub_rn(cur, v)));
            const float id = __fadd_rn(cur, __fmul_rn(-0.2f, cur));
            const bool sp = vd > 1.0f;
            z = sp ? 1.f : 0.f;
            v = sp ? 0.f : vd;
            cur = __fadd_rn(id, x);
        }
    }

    if (last) {
        out[j]           = z;
        out[NB + j]      = z;
        out[2 * NB + j]  = v;
        out[3 * NB + j]  = cur;
    } else {
        vi[j]      = v;
        vi[NB + j] = cur;
    }
}

extern "C" void kernel_launch(void* const* d_in, const int* in_sizes, int n_in,
                              void* d_out, int out_size, void* d_ws, size_t ws_size,
                              hipStream_t stream) {
    const float* S = (const float*)d_in[0];  // [T,B,F] fp32
    const float* W = (const float*)d_in[1];  // [F,F] fp32
    float* out = (float*)d_out;
    float* vi = (float*)d_ws;        // 2*NB floats of state
    float* xs = vi + 2 * NB;         // chunk buffer [Tc, NB]
    // pick largest power-of-two chunk Tc whose xs buffer fits the workspace,
    // then cap at 256 so {xs chunk (67MB) + S chunk (67MB) + W (1MB)} stays
    // resident in the 256MB Infinity Cache: the GEMM->scan xs handoff avoids
    // the HBM round trip entirely.
    const size_t avail_f = (ws_size / 4 > (size_t)(2 * NB)) ? ws_size / 4 - 2 * NB : 0;
    int Tc = T_DIM;
    while (Tc > 1 && (size_t)Tc * NB > avail_f) Tc >>= 1;
    if (Tc > 256) Tc = 256;
    const int nc = T_DIM / Tc;
    for (int c = 0; c < nc; ++c) {
        const int M = Tc * B_DIM;
        dim3 grid(M / TM, F_DIM / TN);
        gemm_kernel<<<grid, 256, 0, stream>>>(S + (size_t)c * Tc * NB, W, xs);
        scan_kernel<<<NB / 256, 256, 0, stream>>>(xs, vi, out, Tc,
                                                  (c == 0) ? 1 : 0,
                                                  (c == nc - 1) ? 1 : 0);
    }
}

// Round 2
// 1031.253 us; speedup vs baseline: 1.0869x; 1.0869x over previous
//
#include <hip/hip_runtime.h>

// LIF benchmark: xs = einsum('tbf,gf->tbg', S, W)  (fp32 GEMM, A=S [T*B,512], B=W [512,512], NT)
// then sequential scan over T with per-neuron (v,i) state and heaviside threshold.
// Outputs: [z_final, z_final, v_final, i_final], each [128,512] fp32.
//
// R7 (session R2):
//   - REVERT R6's Tc=256 chunking (cost +77us: no LLC win -- WRITE_SIZE showed
//     xs still goes through the memory path -- and 4x gemm->scan serialization
//     + small-dispatch tails). Back to single-chunk launcher (R5/R0 logic).
//   - GEMM: KC 32->16 with double-buffered LDS (same 50176B footprint: 2x25KB,
//     occupancy unchanged at 2 blocks/CU). Global loads for tile t+1 issue
//     BEFORE compute of tile t (4096cy compute covers HBM latency); vmcnt wait
//     lands at the LDS stores after compute; ONE barrier per 16-k tile (same
//     total barrier count as the old 2-per-32k). Staging geometry srow=tid>>2,
//     sk=(tid&3)*4 makes store bank = (16j+4q+srow)%32 -> 32 banks x 2 lanes
//     (2-way distinct-address = free, m136), killing the old 4-way write
//     conflict (was 7.3% of CU cycles in SQ_LDS_BANK_CONFLICT).
//   - Compute body / micro-tile / epilogue / FMA order: verbatim R5 (ascending-k
//     fused chains -> absmax 0.0). Scan kernel: verbatim R3/R5.

#define T_DIM 1024
#define B_DIM 128
#define F_DIM 512
#define NB (B_DIM * F_DIM)  // 65536 neurons

// ---------------- GEMM: C[m][n] = sum_k A[m][k] * W[n][k] ----------------
// Block tile 128m x 256n, 256 threads, 8x16 micro-tile, KC=16, double-buffered.
#define TM 128
#define TN 256
#define KC 16
#define LDA_S 132            // As row pad (132%32==4)
#define LDB_S 260            // Bs row pad (260%32==4)
#define A_SZ (KC * LDA_S)    // 2112 floats per buffer
#define B_SZ (KC * LDB_S)    // 4160 floats per buffer

__global__ __launch_bounds__(256, 2)
void gemm_kernel(const float* __restrict__ A, const float* __restrict__ W,
                 float* __restrict__ C) {
    __shared__ float As[2 * A_SZ];  // [buf][k][m]
    __shared__ float Bs[2 * B_SZ];  // [buf][k][n]
    const int tid = threadIdx.x;
    const int m0 = blockIdx.x * TM;
    const int n0 = blockIdx.y * TN;
    const int tn4 = (tid & 15) * 4;  // b cols: tn4 + {0..3} + 64q, q=0..3
    const int tm4 = (tid >> 4) * 4;  // a rows: tm4 + {0..3} and +64
    const int srow = tid >> 2;       // staging row 0..63 (+64p)
    const int sk = (tid & 3) * 4;    // staging k 0,4,8,12

    float acc[8][16];
    #pragma unroll
    for (int i = 0; i < 8; ++i)
        #pragma unroll
        for (int j = 0; j < 16; ++j) acc[i][j] = 0.f;

    // ---- prologue: stage tile k0=0 into buffer 0 ----
    {
        float4 av[2], bv[4];
        #pragma unroll
        for (int p = 0; p < 2; ++p)
            av[p] = *(const float4*)(A + (size_t)(m0 + srow + 64 * p) * F_DIM + sk);
        #pragma unroll
        for (int p = 0; p < 4; ++p)
            bv[p] = *(const float4*)(W + (size_t)(n0 + srow + 64 * p) * F_DIM + sk);
        #pragma unroll
        for (int p = 0; p < 2; ++p) {
            const int r = srow + 64 * p;
            As[(sk + 0) * LDA_S + r] = av[p].x;  As[(sk + 1) * LDA_S + r] = av[p].y;
            As[(sk + 2) * LDA_S + r] = av[p].z;  As[(sk + 3) * LDA_S + r] = av[p].w;
        }
        #pragma unroll
        for (int p = 0; p < 4; ++p) {
            const int r = srow + 64 * p;
            Bs[(sk + 0) * LDB_S + r] = bv[p].x;  Bs[(sk + 1) * LDB_S + r] = bv[p].y;
            Bs[(sk + 2) * LDB_S + r] = bv[p].z;  Bs[(sk + 3) * LDB_S + r] = bv[p].w;
        }
        __syncthreads();
    }

    int cur = 0;
    for (int k0 = 0; k0 < F_DIM; k0 += KC) {
        const bool more = (k0 + KC < F_DIM);
        // issue next tile's global loads BEFORE compute: latency hides under it
        float4 av[2], bv[4];
        if (more) {
            #pragma unroll
            for (int p = 0; p < 2; ++p)
                av[p] = *(const float4*)(A + (size_t)(m0 + srow + 64 * p) * F_DIM
                                           + (k0 + KC) + sk);
            #pragma unroll
            for (int p = 0; p < 4; ++p)
                bv[p] = *(const float4*)(W + (size_t)(n0 + srow + 64 * p) * F_DIM
                                           + (k0 + KC) + sk);
        }

        // ---- compute on buf[cur] ----
        const float* asb = As + cur * A_SZ;
        const float* bsb = Bs + cur * B_SZ;
        #pragma unroll 4
        for (int k = 0; k < KC; ++k) {
            const float4 a0 = *(const float4*)(asb + k * LDA_S + tm4);
            const float4 a1 = *(const float4*)(asb + k * LDA_S + tm4 + 64);
            const float4 b0 = *(const float4*)(bsb + k * LDB_S + tn4);
            const float4 b1 = *(const float4*)(bsb + k * LDB_S + tn4 + 64);
            const float4 b2 = *(const float4*)(bsb + k * LDB_S + tn4 + 128);
            const float4 b3 = *(const float4*)(bsb + k * LDB_S + tn4 + 192);
            const float a[8] = {a0.x, a0.y, a0.z, a0.w, a1.x, a1.y, a1.z, a1.w};
            const float b[16] = {b0.x, b0.y, b0.z, b0.w, b1.x, b1.y, b1.z, b1.w,
                                 b2.x, b2.y, b2.z, b2.w, b3.x, b3.y, b3.z, b3.w};
            #pragma unroll
            for (int i = 0; i < 8; ++i)
                #pragma unroll
                for (int j = 0; j < 16; ++j)
                    acc[i][j] += a[i] * b[j];
        }

        // ---- stage next tile into buf[cur^1]; safe: everyone left it at the
        //      barrier ending tile t-1 ----
        if (more) {
            float* asn = As + (cur ^ 1) * A_SZ;
            float* bsn = Bs + (cur ^ 1) * B_SZ;
            #pragma unroll
            for (int p = 0; p < 2; ++p) {
                const int r = srow + 64 * p;
                asn[(sk + 0) * LDA_S + r] = av[p].x;  asn[(sk + 1) * LDA_S + r] = av[p].y;
                asn[(sk + 2) * LDA_S + r] = av[p].z;  asn[(sk + 3) * LDA_S + r] = av[p].w;
            }
            #pragma unroll
            for (int p = 0; p < 4; ++p) {
                const int r = srow + 64 * p;
                bsn[(sk + 0) * LDB_S + r] = bv[p].x;  bsn[(sk + 1) * LDB_S + r] = bv[p].y;
                bsn[(sk + 2) * LDB_S + r] = bv[p].z;  bsn[(sk + 3) * LDB_S + r] = bv[p].w;
            }
            __syncthreads();
            cur ^= 1;
        }
    }

    #pragma unroll
    for (int i = 0; i < 8; ++i) {
        const int m = m0 + ((i < 4) ? (tm4 + i) : (tm4 + 60 + i));  // tm4+64+(i-4)
        #pragma unroll
        for (int q = 0; q < 4; ++q) {
            const float4 c = make_float4(acc[i][4 * q + 0], acc[i][4 * q + 1],
                                         acc[i][4 * q + 2], acc[i][4 * q + 3]);
            *(float4*)(C + (size_t)m * F_DIM + n0 + tn4 + 64 * q) = c;
        }
    }
}

// ---------------- sequential LIF scan over a chunk of Tc steps ----------------
// Verbatim R3/R5 (passed): depth-32 register ring buffer.
// Explicit _rn intrinsics: forbid fma contraction (matches reference rounding).
#define DEPTH 32

__global__ __launch_bounds__(256)
void scan_kernel(const float* __restrict__ xs, float* __restrict__ vi,
                 float* __restrict__ out, int Tc, int first, int last) {
    const int j = blockIdx.x * 256 + threadIdx.x;  // neuron id, 0..NB-1
    float v, cur;
    if (first) { v = 0.f; cur = 0.f; }
    else       { v = vi[j]; cur = vi[NB + j]; }
    float z = 0.f;
    const float* pj = xs + j;

    if (Tc >= DEPTH && (Tc % DEPTH) == 0) {
        float buf[DEPTH];
        #pragma unroll
        for (int d = 0; d < DEPTH; ++d) buf[d] = pj[(size_t)d * NB];
        for (int tt = 0; tt < Tc; tt += DEPTH) {
            #pragma unroll
            for (int d = 0; d < DEPTH; ++d) {
                const float x = buf[d];
                int tn = tt + DEPTH + d;
                tn = (tn < Tc) ? tn : 0;          // clamped dead prefetch at tail
                buf[d] = pj[(size_t)tn * NB];
                const float vd = __fadd_rn(v, __fmul_rn(0.1f, __fsub_rn(cur, v)));
                const float id = __fadd_rn(cur, __fmul_rn(-0.2f, cur));
                const bool sp = vd > 1.0f;
                z = sp ? 1.f : 0.f;
                v = sp ? 0.f : vd;
                cur = __fadd_rn(id, x);
            }
        }
    } else {
        for (int t = 0; t < Tc; ++t) {
            const float x = pj[(size_t)t * NB];
            const float vd = __fadd_rn(v, __fmul_rn(0.1f, __fsub_rn(cur, v)));
            const float id = __fadd_rn(cur, __fmul_rn(-0.2f, cur));
            const bool sp = vd > 1.0f;
            z = sp ? 1.f : 0.f;
            v = sp ? 0.f : vd;
            cur = __fadd_rn(id, x);
        }
    }

    if (last) {
        out[j]           = z;
        out[NB + j]      = z;
        out[2 * NB + j]  = v;
        out[3 * NB + j]  = cur;
    } else {
        vi[j]      = v;
        vi[NB + j] = cur;
    }
}

extern "C" void kernel_launch(void* const* d_in, const int* in_sizes, int n_in,
                              void* d_out, int out_size, void* d_ws, size_t ws_size,
                              hipStream_t stream) {
    const float* S = (const float*)d_in[0];  // [T,B,F] fp32
    const float* W = (const float*)d_in[1];  // [F,F] fp32
    float* out = (float*)d_out;
    float* vi = (float*)d_ws;        // 2*NB floats of state
    float* xs = vi + 2 * NB;         // chunk buffer [Tc, NB]
    // pick largest power-of-two chunk Tc whose xs buffer fits the workspace
    const size_t avail_f = (ws_size / 4 > (size_t)(2 * NB)) ? ws_size / 4 - 2 * NB : 0;
    int Tc = T_DIM;
    while (Tc > 1 && (size_t)Tc * NB > avail_f) Tc >>= 1;
    const int nc = T_DIM / Tc;
    for (int c = 0; c < nc; ++c) {
        const int M = Tc * B_DIM;
        dim3 grid(M / TM, F_DIM / TN);
        gemm_kernel<<<grid, 256, 0, stream>>>(S + (size_t)c * Tc * NB, W, xs);
        scan_kernel<<<NB / 256, 256, 0, stream>>>(xs, vi, out, Tc,
                                                  (c == 0) ? 1 : 0,
                                                  (c == nc - 1) ? 1 : 0);
    }
}